// Round 3
// baseline (438.974 us; speedup 1.0000x reference)
//
#include <hip/hip_runtime.h>
#include <math.h>

#define H_ 128
#define W_ 160
#define D_ 48
#define C_ 32
#define K27 27
#define HW_ (H_ * W_)
#define DHW_ (D_ * HW_)
#define CHW_ (C_ * HW_)

typedef float f4 __attribute__((ext_vector_type(4)));
typedef float f4u __attribute__((ext_vector_type(4))) __attribute__((aligned(4)));

// ---------------------------------------------------------------------------
// Kernel 1: projection setup (unchanged). For each src view v=1..4 store
// 12 floats: rot(9) + trans(3) of  src_proj_new @ inv(ref_proj_new).
// ---------------------------------------------------------------------------
__device__ __forceinline__ void build_proj(const float* __restrict__ P, int v,
                                           double M[4][4]) {
    const float* E = P + (v * 2 + 0) * 16;
    const float* K = P + (v * 2 + 1) * 16;
    for (int i = 0; i < 3; i++)
        for (int j = 0; j < 4; j++) {
            double s = 0.0;
            for (int k = 0; k < 3; k++) s += (double)K[i * 4 + k] * (double)E[k * 4 + j];
            M[i][j] = s;
        }
    for (int j = 0; j < 4; j++) M[3][j] = (double)E[12 + j];
}

__global__ void proj_kernel(const float* __restrict__ P, float* __restrict__ rt) {
    if (threadIdx.x != 0) return;
    double M0[4][4];
    build_proj(P, 0, M0);
    double a[4][8];
    for (int i = 0; i < 4; i++)
        for (int j = 0; j < 4; j++) {
            a[i][j] = M0[i][j];
            a[i][4 + j] = (i == j) ? 1.0 : 0.0;
        }
    for (int col = 0; col < 4; ++col) {
        int piv = col;
        double best = fabs(a[col][col]);
        for (int r = col + 1; r < 4; r++) {
            double vv = fabs(a[r][col]);
            if (vv > best) { best = vv; piv = r; }
        }
        if (piv != col)
            for (int j = 0; j < 8; j++) {
                double t = a[col][j]; a[col][j] = a[piv][j]; a[piv][j] = t;
            }
        double inv = 1.0 / a[col][col];
        for (int j = 0; j < 8; j++) a[col][j] *= inv;
        for (int r = 0; r < 4; r++)
            if (r != col) {
                double f = a[r][col];
                for (int j = 0; j < 8; j++) a[r][j] -= f * a[col][j];
            }
    }
    double Minv[4][4];
    for (int i = 0; i < 4; i++)
        for (int j = 0; j < 4; j++) Minv[i][j] = a[i][4 + j];

    for (int v = 1; v < 5; ++v) {
        double Mv[4][4];
        build_proj(P, v, Mv);
        double Pm[4][4];
        for (int i = 0; i < 4; i++)
            for (int j = 0; j < 4; j++) {
                double s = 0.0;
                for (int k = 0; k < 4; k++) s += Mv[i][k] * Minv[k][j];
                Pm[i][j] = s;
            }
        float* o = rt + (v - 1) * 12;
        o[0] = (float)Pm[0][0]; o[1] = (float)Pm[0][1]; o[2] = (float)Pm[0][2];
        o[3] = (float)Pm[1][0]; o[4] = (float)Pm[1][1]; o[5] = (float)Pm[1][2];
        o[6] = (float)Pm[2][0]; o[7] = (float)Pm[2][1]; o[8] = (float)Pm[2][2];
        o[9] = (float)Pm[0][3]; o[10] = (float)Pm[1][3]; o[11] = (float)Pm[2][3];
    }
}

// ---------------------------------------------------------------------------
// Kernel 1b: transpose [4][C][HW] -> [4][HW][C]  (channels-last)
// Coalesced reads per channel plane; each thread writes 128B contiguous.
// ---------------------------------------------------------------------------
__global__ void transpose_kernel(const float* __restrict__ in,
                                 float* __restrict__ out) {
    int t = blockIdx.x * blockDim.x + threadIdx.x;
    if (t >= 4 * HW_) return;
    int pix = t % HW_;
    int v = t / HW_;
    float vals[C_];
#pragma unroll
    for (int c = 0; c < C_; c++) vals[c] = in[(size_t)v * CHW_ + c * HW_ + pix];
    f4* o = (f4*)(out + ((size_t)v * HW_ + pix) * C_);
#pragma unroll
    for (int q = 0; q < 8; q++) {
        f4 w = {vals[4 * q], vals[4 * q + 1], vals[4 * q + 2], vals[4 * q + 3]};
        o[q] = w;
    }
}

// ---------------------------------------------------------------------------
// Kernel 2: warp + bilinear + ref*warped accumulate over 4 views (channels-
// last float4 loads), then fold channels through conv weights in registers.
// ---------------------------------------------------------------------------
__global__ void warp_fold_kernel(const float* __restrict__ srcT,
                                 const float* __restrict__ refT,
                                 const float* __restrict__ rt,
                                 const float* __restrict__ dvals,
                                 const float* __restrict__ wreg,
                                 float* __restrict__ G) {
    int idx = blockIdx.x * blockDim.x + threadIdx.x;
    if (idx >= DHW_) return;
    int x = idx % W_;
    int y = (idx / W_) % H_;
    int d = idx / HW_;
    float depth = dvals[d];
    float xf = (float)x, yf = (float)y;
    int pix = y * W_ + x;

    f4 acc4[8];
#pragma unroll
    for (int q = 0; q < 8; q++) acc4[q] = (f4){0.f, 0.f, 0.f, 0.f};

#pragma unroll 1
    for (int v = 0; v < 4; v++) {
        const float* m = rt + v * 12;
        float px = fmaf(fmaf(m[0], xf, fmaf(m[1], yf, m[2])), depth, m[9]);
        float py = fmaf(fmaf(m[3], xf, fmaf(m[4], yf, m[5])), depth, m[10]);
        float pz = fmaf(fmaf(m[6], xf, fmaf(m[7], yf, m[8])), depth, m[11]);
        float iz = 1.f / pz;
        px *= iz;
        py *= iz;
        float x0f = floorf(px), y0f = floorf(py);
        float wx = px - x0f, wy = py - y0f;
        int x0 = (int)x0f, y0 = (int)y0f;
        int x1 = x0 + 1, y1 = y0 + 1;

        float w00 = (1.f - wx) * (1.f - wy);
        float w10 = wx * (1.f - wy);
        float w01 = (1.f - wx) * wy;
        float w11 = wx * wy;
        bool vx0 = (x0 >= 0) && (x0 < W_);
        bool vx1 = (x1 >= 0) && (x1 < W_);
        bool vy0 = (y0 >= 0) && (y0 < H_);
        bool vy1 = (y1 >= 0) && (y1 < H_);
        if (!(vx0 && vy0)) w00 = 0.f;
        if (!(vx1 && vy0)) w10 = 0.f;
        if (!(vx0 && vy1)) w01 = 0.f;
        if (!(vx1 && vy1)) w11 = 0.f;
        int cx0 = min(max(x0, 0), W_ - 1);
        int cx1 = min(max(x1, 0), W_ - 1);
        int cy0 = min(max(y0, 0), H_ - 1);
        int cy1 = min(max(y1, 0), H_ - 1);

        const f4* p00 = (const f4*)(srcT + ((size_t)v * HW_ + cy0 * W_ + cx0) * C_);
        const f4* p10 = (const f4*)(srcT + ((size_t)v * HW_ + cy0 * W_ + cx1) * C_);
        const f4* p01 = (const f4*)(srcT + ((size_t)v * HW_ + cy1 * W_ + cx0) * C_);
        const f4* p11 = (const f4*)(srcT + ((size_t)v * HW_ + cy1 * W_ + cx1) * C_);
        const f4* pr  = (const f4*)(refT + ((size_t)v * HW_ + pix) * C_);

#pragma unroll
        for (int q = 0; q < 8; q++) {
            f4 a00 = p00[q];
            f4 a10 = p10[q];
            f4 a01 = p01[q];
            f4 a11 = p11[q];
            f4 rr = pr[q];
            f4 sv = a00 * w00 + a10 * w10 + a01 * w01 + a11 * w11;
            acc4[q] += rr * sv;
        }
    }

    // fold channels through conv weights (wave-uniform -> scalar loads)
    float g[K27];
#pragma unroll
    for (int k = 0; k < K27; k++) g[k] = 0.f;
#pragma unroll
    for (int q = 0; q < 8; q++) {
#pragma unroll
        for (int j = 0; j < 4; j++) {
            float a = acc4[q][j] * 0.25f;
            const float* wc = wreg + (q * 4 + j) * K27;
#pragma unroll
            for (int k = 0; k < K27; k++) g[k] = fmaf(wc[k], a, g[k]);
        }
    }
#pragma unroll
    for (int k = 0; k < K27; k++) G[(size_t)k * DHW_ + idx] = g[k];
}

// ---------------------------------------------------------------------------
// Kernel 3: gather-conv, vectorized x4 along x. cost[d,y,x..x+3] = sum over
// 27 taps of the corresponding G plane at shifted voxels (zero outside).
// ---------------------------------------------------------------------------
__global__ void gather_conv_kernel(const float* __restrict__ G,
                                   float* __restrict__ cost) {
    int t = blockIdx.x * blockDim.x + threadIdx.x;
    if (t >= DHW_ / 4) return;
    int idx = t * 4;
    int x = idx % W_;            // multiple of 4
    int y = (idx / W_) % H_;
    int d = idx / HW_;
    f4 acc = (f4){0.f, 0.f, 0.f, 0.f};
#pragma unroll
    for (int kd = 0; kd < 3; kd++) {
        int dd = d + kd - 1;
        if ((unsigned)dd >= (unsigned)D_) continue;
#pragma unroll
        for (int kh = 0; kh < 3; kh++) {
            int yy = y + kh - 1;
            if ((unsigned)yy >= (unsigned)H_) continue;
#pragma unroll
            for (int kw = 0; kw < 3; kw++) {
                int k = (kd * 3 + kh) * 3 + kw;
                const float* row = G + (size_t)k * DHW_ + dd * HW_ + yy * W_;
                int xx0 = x + kw - 1;
                f4 val;
                if (xx0 >= 0 && xx0 + 3 < W_) {
                    val = *(const f4u*)(row + xx0);
                } else {
#pragma unroll
                    for (int j = 0; j < 4; j++) {
                        int xx = xx0 + j;
                        val[j] = ((unsigned)xx < (unsigned)W_) ? row[xx] : 0.f;
                    }
                }
                acc += val;
            }
        }
    }
    *(f4*)(cost + idx) = acc;
}

// ---------------------------------------------------------------------------
// Kernel 4: per-pixel softmax over D, expected depth, windowed confidence.
// ---------------------------------------------------------------------------
__global__ void softmax_kernel(const float* __restrict__ cost,
                               const float* __restrict__ dvals,
                               float* __restrict__ out) {
    int pix = blockIdx.x * blockDim.x + threadIdx.x;
    if (pix >= HW_) return;
    float mx = -1e30f;
#pragma unroll 1
    for (int d = 0; d < D_; d++) mx = fmaxf(mx, cost[d * HW_ + pix]);
    float s = 0.f, dnum = 0.f, inum = 0.f;
#pragma unroll 1
    for (int d = 0; d < D_; d++) {
        float e = __expf(cost[d * HW_ + pix] - mx);
        s += e;
        dnum = fmaf(e, dvals[d], dnum);
        inum = fmaf(e, (float)d, inum);
    }
    float invs = 1.f / s;
    float depth = dnum * invs;
    float didx = inum * invs;
    int id = (int)didx;
    id = min(max(id, 0), D_ - 1);
    float conf = 0.f;
    for (int k = id - 1; k <= id + 2; ++k)
        if (k >= 0 && k < D_) conf += __expf(cost[k * HW_ + pix] - mx);
    conf *= invs;
    out[pix] = depth;
    out[HW_ + pix] = conf;
}

// ---------------------------------------------------------------------------
extern "C" void kernel_launch(void* const* d_in, const int* in_sizes, int n_in,
                              void* d_out, int out_size, void* d_ws, size_t ws_size,
                              hipStream_t stream) {
    const float* ref_feats = (const float*)d_in[0];   // (4,1,32,128,160)
    const float* src_feats = (const float*)d_in[1];   // (4,1,32,128,160)
    const float* proj      = (const float*)d_in[2];   // (1,5,2,4,4)
    const float* dvals     = (const float*)d_in[3];   // (1,48)
    const float* wreg      = (const float*)d_in[5];   // (1,32,3,3,3)
    float* out = (float*)d_out;                       // depth(20480) ++ conf(20480)

    char* ws = (char*)d_ws;
    float* rt   = (float*)ws;                          // 48 floats (pad to 1KB)
    float* srcT = (float*)(ws + 1024);                 // 4*HW*32*4 = 10.5 MB
    float* refT = srcT + (size_t)4 * HW_ * C_;         // 10.5 MB
    float* G    = refT + (size_t)4 * HW_ * C_;         // 27*DHW*4 = 106 MB
    float* cost = G + (size_t)K27 * DHW_;              // 3.9 MB

    proj_kernel<<<1, 64, 0, stream>>>(proj, rt);
    transpose_kernel<<<(4 * HW_) / 256, 256, 0, stream>>>(src_feats, srcT);
    transpose_kernel<<<(4 * HW_) / 256, 256, 0, stream>>>(ref_feats, refT);
    warp_fold_kernel<<<DHW_ / 256, 256, 0, stream>>>(srcT, refT, rt, dvals, wreg, G);
    gather_conv_kernel<<<(DHW_ / 4) / 256, 256, 0, stream>>>(G, cost);
    softmax_kernel<<<HW_ / 256, 256, 0, stream>>>(cost, dvals, out);
}

// Round 4
// 239.448 us; speedup vs baseline: 1.8333x; 1.8333x over previous
//
#include <hip/hip_runtime.h>
#include <math.h>

#define H_ 128
#define W_ 160
#define D_ 48
#define C_ 32
#define K27 27
#define HW_ (H_ * W_)
#define DHW_ (D_ * HW_)
#define CHW_ (C_ * HW_)

typedef float f4 __attribute__((ext_vector_type(4)));
typedef float f4u __attribute__((ext_vector_type(4))) __attribute__((aligned(4)));

// ---------------------------------------------------------------------------
// Kernel 1: projection setup. For each src view v=1..4 store 12 floats:
// rot(9) + trans(3) of  src_proj_new @ inv(ref_proj_new).
// ---------------------------------------------------------------------------
__device__ __forceinline__ void build_proj(const float* __restrict__ P, int v,
                                           double M[4][4]) {
    const float* E = P + (v * 2 + 0) * 16;
    const float* K = P + (v * 2 + 1) * 16;
    for (int i = 0; i < 3; i++)
        for (int j = 0; j < 4; j++) {
            double s = 0.0;
            for (int k = 0; k < 3; k++) s += (double)K[i * 4 + k] * (double)E[k * 4 + j];
            M[i][j] = s;
        }
    for (int j = 0; j < 4; j++) M[3][j] = (double)E[12 + j];
}

__global__ void proj_kernel(const float* __restrict__ P, float* __restrict__ rt) {
    if (threadIdx.x != 0) return;
    double M0[4][4];
    build_proj(P, 0, M0);
    double a[4][8];
    for (int i = 0; i < 4; i++)
        for (int j = 0; j < 4; j++) {
            a[i][j] = M0[i][j];
            a[i][4 + j] = (i == j) ? 1.0 : 0.0;
        }
    for (int col = 0; col < 4; ++col) {
        int piv = col;
        double best = fabs(a[col][col]);
        for (int r = col + 1; r < 4; r++) {
            double vv = fabs(a[r][col]);
            if (vv > best) { best = vv; piv = r; }
        }
        if (piv != col)
            for (int j = 0; j < 8; j++) {
                double t = a[col][j]; a[col][j] = a[piv][j]; a[piv][j] = t;
            }
        double inv = 1.0 / a[col][col];
        for (int j = 0; j < 8; j++) a[col][j] *= inv;
        for (int r = 0; r < 4; r++)
            if (r != col) {
                double f = a[r][col];
                for (int j = 0; j < 8; j++) a[r][j] -= f * a[col][j];
            }
    }
    double Minv[4][4];
    for (int i = 0; i < 4; i++)
        for (int j = 0; j < 4; j++) Minv[i][j] = a[i][4 + j];

    for (int v = 1; v < 5; ++v) {
        double Mv[4][4];
        build_proj(P, v, Mv);
        double Pm[4][4];
        for (int i = 0; i < 4; i++)
            for (int j = 0; j < 4; j++) {
                double s = 0.0;
                for (int k = 0; k < 4; k++) s += Mv[i][k] * Minv[k][j];
                Pm[i][j] = s;
            }
        float* o = rt + (v - 1) * 12;
        o[0] = (float)Pm[0][0]; o[1] = (float)Pm[0][1]; o[2] = (float)Pm[0][2];
        o[3] = (float)Pm[1][0]; o[4] = (float)Pm[1][1]; o[5] = (float)Pm[1][2];
        o[6] = (float)Pm[2][0]; o[7] = (float)Pm[2][1]; o[8] = (float)Pm[2][2];
        o[9] = (float)Pm[0][3]; o[10] = (float)Pm[1][3]; o[11] = (float)Pm[2][3];
    }
}

// ---------------------------------------------------------------------------
// Kernel 1b: transpose [4][C][HW] -> [4][HW][C]  (channels-last)
// ---------------------------------------------------------------------------
__global__ void transpose_kernel(const float* __restrict__ in,
                                 float* __restrict__ out) {
    int t = blockIdx.x * blockDim.x + threadIdx.x;
    if (t >= 4 * HW_) return;
    int pix = t % HW_;
    int v = t / HW_;
    float vals[C_];
#pragma unroll
    for (int c = 0; c < C_; c++) vals[c] = in[(size_t)v * CHW_ + c * HW_ + pix];
    f4* o = (f4*)(out + ((size_t)v * HW_ + pix) * C_);
#pragma unroll
    for (int q = 0; q < 8; q++) {
        f4 w = {vals[4 * q], vals[4 * q + 1], vals[4 * q + 2], vals[4 * q + 3]};
        o[q] = w;
    }
}

// ---------------------------------------------------------------------------
// Kernel 2: warp + bilinear + ref*warped + channel-fold.
// Block = 256 threads = 64 voxels x 4 channel-groups (8 ch/thread).
// Phase 1: each thread computes acc for its 8 channels of its voxel
//          (coalesced b128 loads: 4 lanes of a voxel read contiguous 128B).
//          Writes acc to LDS accT[cq][vox][4] (16B-stride minimal pattern).
// Phase 2: 4 waves x 64 voxels; each wave owns a wave-uniform k-range of the
//          27 conv taps -> weights come from SGPRs (s_load), fold is pure
//          v_fmac, G stores fully coalesced (256B per instruction).
// ---------------------------------------------------------------------------
__global__ void __launch_bounds__(256)
warp_fold_kernel(const float* __restrict__ srcT,
                 const float* __restrict__ refT,
                 const float* __restrict__ rt,
                 const float* __restrict__ dvals,
                 const float* __restrict__ wreg,
                 float* __restrict__ G) {
    __shared__ float accT[8][64][4];   // [c-chunk][voxel][4 floats] = 8KB

    int t = threadIdx.x;
    int vox = t >> 2;          // 0..63
    int cgrp = t & 3;          // 0..3 -> channels cgrp*8 .. cgrp*8+7
    int idx = blockIdx.x * 64 + vox;   // DHW_ = 64 * 15360 exactly
    int x = idx % W_;
    int y = (idx / W_) % H_;
    int d = idx / HW_;
    float depth = dvals[d];
    float xf = (float)x, yf = (float)y;
    int pix = y * W_ + x;

    f4 acc0 = (f4){0.f, 0.f, 0.f, 0.f};
    f4 acc1 = (f4){0.f, 0.f, 0.f, 0.f};

#pragma unroll 2
    for (int v = 0; v < 4; v++) {
        const float* m = rt + v * 12;
        float px = fmaf(fmaf(m[0], xf, fmaf(m[1], yf, m[2])), depth, m[9]);
        float py = fmaf(fmaf(m[3], xf, fmaf(m[4], yf, m[5])), depth, m[10]);
        float pz = fmaf(fmaf(m[6], xf, fmaf(m[7], yf, m[8])), depth, m[11]);
        float iz = 1.f / pz;
        px *= iz;
        py *= iz;
        float x0f = floorf(px), y0f = floorf(py);
        float wx = px - x0f, wy = py - y0f;
        int x0 = (int)x0f, y0 = (int)y0f;
        int x1 = x0 + 1, y1 = y0 + 1;

        float w00 = (1.f - wx) * (1.f - wy);
        float w10 = wx * (1.f - wy);
        float w01 = (1.f - wx) * wy;
        float w11 = wx * wy;
        bool vx0 = (x0 >= 0) && (x0 < W_);
        bool vx1 = (x1 >= 0) && (x1 < W_);
        bool vy0 = (y0 >= 0) && (y0 < H_);
        bool vy1 = (y1 >= 0) && (y1 < H_);
        if (!(vx0 && vy0)) w00 = 0.f;
        if (!(vx1 && vy0)) w10 = 0.f;
        if (!(vx0 && vy1)) w01 = 0.f;
        if (!(vx1 && vy1)) w11 = 0.f;
        int cx0 = min(max(x0, 0), W_ - 1);
        int cx1 = min(max(x1, 0), W_ - 1);
        int cy0 = min(max(y0, 0), H_ - 1);
        int cy1 = min(max(y1, 0), H_ - 1);

        const f4* p00 = (const f4*)(srcT + ((size_t)v * HW_ + cy0 * W_ + cx0) * C_ + cgrp * 8);
        const f4* p10 = (const f4*)(srcT + ((size_t)v * HW_ + cy0 * W_ + cx1) * C_ + cgrp * 8);
        const f4* p01 = (const f4*)(srcT + ((size_t)v * HW_ + cy1 * W_ + cx0) * C_ + cgrp * 8);
        const f4* p11 = (const f4*)(srcT + ((size_t)v * HW_ + cy1 * W_ + cx1) * C_ + cgrp * 8);
        const f4* pr  = (const f4*)(refT + ((size_t)v * HW_ + pix) * C_ + cgrp * 8);

        f4 a00 = p00[0], b00 = p00[1];
        f4 a10 = p10[0], b10 = p10[1];
        f4 a01 = p01[0], b01 = p01[1];
        f4 a11 = p11[0], b11 = p11[1];
        f4 r0 = pr[0],  r1 = pr[1];

        f4 sv0 = a00 * w00 + a10 * w10 + a01 * w01 + a11 * w11;
        f4 sv1 = b00 * w00 + b10 * w10 + b01 * w01 + b11 * w11;
        acc0 += r0 * sv0;
        acc1 += r1 * sv1;
    }
    acc0 *= 0.25f;
    acc1 *= 0.25f;

    int cq0 = cgrp * 2;
    *(f4*)&accT[cq0][vox][0] = acc0;
    *(f4*)&accT[cq0 + 1][vox][0] = acc1;
    __syncthreads();

    // ---- phase 2: fold channels through conv weights, wave-uniform k ----
    int wid = t >> 6;     // 0..3
    int lane = t & 63;    // voxel slot
    float av[C_];
#pragma unroll
    for (int cq = 0; cq < 8; cq++)
        *(f4*)&av[cq * 4] = *(const f4*)&accT[cq][lane][0];

    int gbase = blockIdx.x * 64 + lane;
    int kstart = wid * 7;
    int kend = min(kstart + 7, K27);
#pragma unroll 1
    for (int k = kstart; k < kend; k++) {
        int ku = __builtin_amdgcn_readfirstlane(k);
        float g = 0.f;
#pragma unroll
        for (int c = 0; c < C_; c++) g = fmaf(wreg[c * K27 + ku], av[c], g);
        G[(size_t)ku * DHW_ + gbase] = g;
    }
}

// ---------------------------------------------------------------------------
// Kernel 3: gather-conv, vectorized x4 along x. cost[d,y,x..x+3] = sum over
// 27 taps of the corresponding G plane at shifted voxels (zero outside).
// ---------------------------------------------------------------------------
__global__ void gather_conv_kernel(const float* __restrict__ G,
                                   float* __restrict__ cost) {
    int t = blockIdx.x * blockDim.x + threadIdx.x;
    if (t >= DHW_ / 4) return;
    int idx = t * 4;
    int x = idx % W_;            // multiple of 4
    int y = (idx / W_) % H_;
    int d = idx / HW_;
    f4 acc = (f4){0.f, 0.f, 0.f, 0.f};
#pragma unroll
    for (int kd = 0; kd < 3; kd++) {
        int dd = d + kd - 1;
        if ((unsigned)dd >= (unsigned)D_) continue;
#pragma unroll
        for (int kh = 0; kh < 3; kh++) {
            int yy = y + kh - 1;
            if ((unsigned)yy >= (unsigned)H_) continue;
#pragma unroll
            for (int kw = 0; kw < 3; kw++) {
                int k = (kd * 3 + kh) * 3 + kw;
                const float* row = G + (size_t)k * DHW_ + dd * HW_ + yy * W_;
                int xx0 = x + kw - 1;
                f4 val;
                if (xx0 >= 0 && xx0 + 3 < W_) {
                    val = *(const f4u*)(row + xx0);
                } else {
#pragma unroll
                    for (int j = 0; j < 4; j++) {
                        int xx = xx0 + j;
                        val[j] = ((unsigned)xx < (unsigned)W_) ? row[xx] : 0.f;
                    }
                }
                acc += val;
            }
        }
    }
    *(f4*)(cost + idx) = acc;
}

// ---------------------------------------------------------------------------
// Kernel 4: per-pixel softmax over D, expected depth, windowed confidence.
// ---------------------------------------------------------------------------
__global__ void softmax_kernel(const float* __restrict__ cost,
                               const float* __restrict__ dvals,
                               float* __restrict__ out) {
    int pix = blockIdx.x * blockDim.x + threadIdx.x;
    if (pix >= HW_) return;
    float mx = -1e30f;
#pragma unroll 1
    for (int d = 0; d < D_; d++) mx = fmaxf(mx, cost[d * HW_ + pix]);
    float s = 0.f, dnum = 0.f, inum = 0.f;
#pragma unroll 1
    for (int d = 0; d < D_; d++) {
        float e = __expf(cost[d * HW_ + pix] - mx);
        s += e;
        dnum = fmaf(e, dvals[d], dnum);
        inum = fmaf(e, (float)d, inum);
    }
    float invs = 1.f / s;
    float depth = dnum * invs;
    float didx = inum * invs;
    int id = (int)didx;
    id = min(max(id, 0), D_ - 1);
    float conf = 0.f;
    for (int k = id - 1; k <= id + 2; ++k)
        if (k >= 0 && k < D_) conf += __expf(cost[k * HW_ + pix] - mx);
    conf *= invs;
    out[pix] = depth;
    out[HW_ + pix] = conf;
}

// ---------------------------------------------------------------------------
extern "C" void kernel_launch(void* const* d_in, const int* in_sizes, int n_in,
                              void* d_out, int out_size, void* d_ws, size_t ws_size,
                              hipStream_t stream) {
    const float* ref_feats = (const float*)d_in[0];   // (4,1,32,128,160)
    const float* src_feats = (const float*)d_in[1];   // (4,1,32,128,160)
    const float* proj      = (const float*)d_in[2];   // (1,5,2,4,4)
    const float* dvals     = (const float*)d_in[3];   // (1,48)
    const float* wreg      = (const float*)d_in[5];   // (1,32,3,3,3)
    float* out = (float*)d_out;                       // depth(20480) ++ conf(20480)

    char* ws = (char*)d_ws;
    float* rt   = (float*)ws;                          // 48 floats (pad to 1KB)
    float* srcT = (float*)(ws + 1024);                 // 4*HW*32*4 = 10.5 MB
    float* refT = srcT + (size_t)4 * HW_ * C_;         // 10.5 MB
    float* G    = refT + (size_t)4 * HW_ * C_;         // 27*DHW*4 = 106 MB
    float* cost = G + (size_t)K27 * DHW_;              // 3.9 MB

    proj_kernel<<<1, 64, 0, stream>>>(proj, rt);
    transpose_kernel<<<(4 * HW_) / 256, 256, 0, stream>>>(src_feats, srcT);
    transpose_kernel<<<(4 * HW_) / 256, 256, 0, stream>>>(ref_feats, refT);
    warp_fold_kernel<<<DHW_ / 64, 256, 0, stream>>>(srcT, refT, rt, dvals, wreg, G);
    gather_conv_kernel<<<(DHW_ / 4) / 256, 256, 0, stream>>>(G, cost);
    softmax_kernel<<<HW_ / 256, 256, 0, stream>>>(cost, dvals, out);
}

// Round 5
// 217.199 us; speedup vs baseline: 2.0211x; 1.1024x over previous
//
#include <hip/hip_runtime.h>
#include <math.h>

#define H_ 128
#define W_ 160
#define D_ 48
#define C_ 32
#define K27 27
#define HW_ (H_ * W_)
#define DHW_ (D_ * HW_)
#define CHW_ (C_ * HW_)

typedef float f4 __attribute__((ext_vector_type(4)));

// ---------------------------------------------------------------------------
// Kernel 1: projection setup. For each src view v=1..4 store 12 floats:
// rot(9) + trans(3) of  src_proj_new @ inv(ref_proj_new).
// ---------------------------------------------------------------------------
__device__ __forceinline__ void build_proj(const float* __restrict__ P, int v,
                                           double M[4][4]) {
    const float* E = P + (v * 2 + 0) * 16;
    const float* K = P + (v * 2 + 1) * 16;
    for (int i = 0; i < 3; i++)
        for (int j = 0; j < 4; j++) {
            double s = 0.0;
            for (int k = 0; k < 3; k++) s += (double)K[i * 4 + k] * (double)E[k * 4 + j];
            M[i][j] = s;
        }
    for (int j = 0; j < 4; j++) M[3][j] = (double)E[12 + j];
}

__global__ void proj_kernel(const float* __restrict__ P, float* __restrict__ rt) {
    if (threadIdx.x != 0) return;
    double M0[4][4];
    build_proj(P, 0, M0);
    double a[4][8];
    for (int i = 0; i < 4; i++)
        for (int j = 0; j < 4; j++) {
            a[i][j] = M0[i][j];
            a[i][4 + j] = (i == j) ? 1.0 : 0.0;
        }
    for (int col = 0; col < 4; ++col) {
        int piv = col;
        double best = fabs(a[col][col]);
        for (int r = col + 1; r < 4; r++) {
            double vv = fabs(a[r][col]);
            if (vv > best) { best = vv; piv = r; }
        }
        if (piv != col)
            for (int j = 0; j < 8; j++) {
                double t = a[col][j]; a[col][j] = a[piv][j]; a[piv][j] = t;
            }
        double inv = 1.0 / a[col][col];
        for (int j = 0; j < 8; j++) a[col][j] *= inv;
        for (int r = 0; r < 4; r++)
            if (r != col) {
                double f = a[r][col];
                for (int j = 0; j < 8; j++) a[r][j] -= f * a[col][j];
            }
    }
    double Minv[4][4];
    for (int i = 0; i < 4; i++)
        for (int j = 0; j < 4; j++) Minv[i][j] = a[i][4 + j];

    for (int v = 1; v < 5; ++v) {
        double Mv[4][4];
        build_proj(P, v, Mv);
        double Pm[4][4];
        for (int i = 0; i < 4; i++)
            for (int j = 0; j < 4; j++) {
                double s = 0.0;
                for (int k = 0; k < 4; k++) s += Mv[i][k] * Minv[k][j];
                Pm[i][j] = s;
            }
        float* o = rt + (v - 1) * 12;
        o[0] = (float)Pm[0][0]; o[1] = (float)Pm[0][1]; o[2] = (float)Pm[0][2];
        o[3] = (float)Pm[1][0]; o[4] = (float)Pm[1][1]; o[5] = (float)Pm[1][2];
        o[6] = (float)Pm[2][0]; o[7] = (float)Pm[2][1]; o[8] = (float)Pm[2][2];
        o[9] = (float)Pm[0][3]; o[10] = (float)Pm[1][3]; o[11] = (float)Pm[2][3];
    }
}

// ---------------------------------------------------------------------------
// Kernel 1b: transpose [4][C][HW] -> [4][HW][C]  (channels-last)
// ---------------------------------------------------------------------------
__global__ void transpose_kernel(const float* __restrict__ in,
                                 float* __restrict__ out) {
    int t = blockIdx.x * blockDim.x + threadIdx.x;
    if (t >= 4 * HW_) return;
    int pix = t % HW_;
    int v = t / HW_;
    float vals[C_];
#pragma unroll
    for (int c = 0; c < C_; c++) vals[c] = in[(size_t)v * CHW_ + c * HW_ + pix];
    f4* o = (f4*)(out + ((size_t)v * HW_ + pix) * C_);
#pragma unroll
    for (int q = 0; q < 8; q++) {
        f4 w = {vals[4 * q], vals[4 * q + 1], vals[4 * q + 2], vals[4 * q + 3]};
        o[q] = w;
    }
}

// ---------------------------------------------------------------------------
// Kernel 2: one image row (d,y) per block.
// Batch loop (3 x 64 voxels, voxel = row x-position shifted by -1 for halo):
//   phase 1: 64 voxels x 4 ch-groups compute warped+ref-weighted acc (f4
//            coalesced loads), write accT LDS.
//   phase 2: 64 voxels x 4 tap-groups fold channels through conv weights
//            (wave-uniform k -> SGPR weights), write g into gLDS[27][162].
// Phase 3: Gx[j][x] = sum_kw g[j*3+kw][x+kw-1]  -> write 9 planes (35 MB).
// Halo voxels (x=-1,160) produce g=0 (zero padding of the SAME conv).
// ---------------------------------------------------------------------------
__global__ void __launch_bounds__(256)
warp_fold_x_kernel(const float* __restrict__ srcT,
                   const float* __restrict__ refT,
                   const float* __restrict__ rt,
                   const float* __restrict__ dvals,
                   const float* __restrict__ wreg,
                   float* __restrict__ Gx) {
    __shared__ float accT[8][64][4];   // 8 KB
    __shared__ float gLDS[K27][164];   // 17.7 KB

    int t = threadIdx.x;
    int blk = blockIdx.x;          // 0..6143
    int d = blk >> 7;              // / 128
    int y = blk & 127;
    float depth = dvals[d];
    float yf = (float)y;
    int rowbase = d * HW_ + y * W_;

#pragma unroll 1
    for (int b = 0; b < 3; b++) {
        int vox = t >> 2;                 // 0..63
        int cgrp = t & 3;                 // 0..3
        int vg = b * 64 + vox;            // 0..191
        int x = vg - 1;                   // -1..190  (valid image x: 0..159)

        f4 acc0 = (f4){0.f, 0.f, 0.f, 0.f};
        f4 acc1 = (f4){0.f, 0.f, 0.f, 0.f};

        if (x >= 0 && x < W_) {
            float xf = (float)x;
            int pix = y * W_ + x;
#pragma unroll 2
            for (int v = 0; v < 4; v++) {
                const float* m = rt + v * 12;
                float px = fmaf(fmaf(m[0], xf, fmaf(m[1], yf, m[2])), depth, m[9]);
                float py = fmaf(fmaf(m[3], xf, fmaf(m[4], yf, m[5])), depth, m[10]);
                float pz = fmaf(fmaf(m[6], xf, fmaf(m[7], yf, m[8])), depth, m[11]);
                float iz = 1.f / pz;
                px *= iz;
                py *= iz;
                float x0f = floorf(px), y0f = floorf(py);
                float wx = px - x0f, wy = py - y0f;
                int x0 = (int)x0f, y0 = (int)y0f;
                int x1 = x0 + 1, y1 = y0 + 1;

                float w00 = (1.f - wx) * (1.f - wy);
                float w10 = wx * (1.f - wy);
                float w01 = (1.f - wx) * wy;
                float w11 = wx * wy;
                bool vx0 = (x0 >= 0) && (x0 < W_);
                bool vx1 = (x1 >= 0) && (x1 < W_);
                bool vy0 = (y0 >= 0) && (y0 < H_);
                bool vy1 = (y1 >= 0) && (y1 < H_);
                if (!(vx0 && vy0)) w00 = 0.f;
                if (!(vx1 && vy0)) w10 = 0.f;
                if (!(vx0 && vy1)) w01 = 0.f;
                if (!(vx1 && vy1)) w11 = 0.f;
                int cx0 = min(max(x0, 0), W_ - 1);
                int cx1 = min(max(x1, 0), W_ - 1);
                int cy0 = min(max(y0, 0), H_ - 1);
                int cy1 = min(max(y1, 0), H_ - 1);

                const f4* p00 = (const f4*)(srcT + ((size_t)v * HW_ + cy0 * W_ + cx0) * C_ + cgrp * 8);
                const f4* p10 = (const f4*)(srcT + ((size_t)v * HW_ + cy0 * W_ + cx1) * C_ + cgrp * 8);
                const f4* p01 = (const f4*)(srcT + ((size_t)v * HW_ + cy1 * W_ + cx0) * C_ + cgrp * 8);
                const f4* p11 = (const f4*)(srcT + ((size_t)v * HW_ + cy1 * W_ + cx1) * C_ + cgrp * 8);
                const f4* pr  = (const f4*)(refT + ((size_t)v * HW_ + pix) * C_ + cgrp * 8);

                f4 a00 = p00[0], b00 = p00[1];
                f4 a10 = p10[0], b10 = p10[1];
                f4 a01 = p01[0], b01 = p01[1];
                f4 a11 = p11[0], b11 = p11[1];
                f4 r0 = pr[0],  r1 = pr[1];

                f4 sv0 = a00 * w00 + a10 * w10 + a01 * w01 + a11 * w11;
                f4 sv1 = b00 * w00 + b10 * w10 + b01 * w01 + b11 * w11;
                acc0 += r0 * sv0;
                acc1 += r1 * sv1;
            }
            acc0 *= 0.25f;
            acc1 *= 0.25f;
        }

        int cq0 = cgrp * 2;
        *(f4*)&accT[cq0][vox][0] = acc0;
        *(f4*)&accT[cq0 + 1][vox][0] = acc1;
        __syncthreads();

        // ---- phase 2: fold channels, wave-uniform tap ranges ----
        int fvox = t & 63;
        int kg = t >> 6;                   // 0..3
        int fvg = b * 64 + fvox;
        float av[C_];
#pragma unroll
        for (int cq = 0; cq < 8; cq++)
            *(f4*)&av[cq * 4] = *(const f4*)&accT[cq][fvox][0];

        if (fvg < 162) {
            int kstart = kg * 7;
            int kend = min(kstart + 7, K27);
#pragma unroll 1
            for (int k = kstart; k < kend; k++) {
                int ku = __builtin_amdgcn_readfirstlane(k);
                float g = 0.f;
#pragma unroll
                for (int c = 0; c < C_; c++) g = fmaf(wreg[c * K27 + ku], av[c], g);
                gLDS[ku][fvg] = g;
            }
        }
        __syncthreads();   // also protects accT before next batch overwrites
    }

    // ---- phase 3: x-shift-add -> 9 planes ----
    if (t < W_) {
        int x = t;
#pragma unroll
        for (int j = 0; j < 9; j++) {
            float s = gLDS[j * 3 + 0][x] + gLDS[j * 3 + 1][x + 1] +
                      gLDS[j * 3 + 2][x + 2];
            Gx[(size_t)j * DHW_ + rowbase + x] = s;
        }
    }
}

// ---------------------------------------------------------------------------
// Kernel 3: gather over 9 planes with (d,y)-shifts only; x stays aligned.
// cost[d,y,x..x+3] = sum_{kd,kh} Gx[kd*3+kh][d+kd-1][y+kh-1][x..x+3]
// ---------------------------------------------------------------------------
__global__ void gather9_kernel(const float* __restrict__ Gx,
                               float* __restrict__ cost) {
    int t = blockIdx.x * blockDim.x + threadIdx.x;
    if (t >= DHW_ / 4) return;
    int idx = t * 4;
    int x = idx % W_;            // multiple of 4
    int y = (idx / W_) % H_;
    int d = idx / HW_;
    f4 acc = (f4){0.f, 0.f, 0.f, 0.f};
#pragma unroll
    for (int kd = 0; kd < 3; kd++) {
        int dd = d + kd - 1;
        if ((unsigned)dd >= (unsigned)D_) continue;
#pragma unroll
        for (int kh = 0; kh < 3; kh++) {
            int yy = y + kh - 1;
            if ((unsigned)yy >= (unsigned)H_) continue;
            int j = kd * 3 + kh;
            acc += *(const f4*)(Gx + (size_t)j * DHW_ + dd * HW_ + yy * W_ + x);
        }
    }
    *(f4*)(cost + idx) = acc;
}

// ---------------------------------------------------------------------------
// Kernel 4: per-pixel softmax over D, expected depth, windowed confidence.
// ---------------------------------------------------------------------------
__global__ void softmax_kernel(const float* __restrict__ cost,
                               const float* __restrict__ dvals,
                               float* __restrict__ out) {
    int pix = blockIdx.x * blockDim.x + threadIdx.x;
    if (pix >= HW_) return;
    float mx = -1e30f;
#pragma unroll 1
    for (int d = 0; d < D_; d++) mx = fmaxf(mx, cost[d * HW_ + pix]);
    float s = 0.f, dnum = 0.f, inum = 0.f;
#pragma unroll 1
    for (int d = 0; d < D_; d++) {
        float e = __expf(cost[d * HW_ + pix] - mx);
        s += e;
        dnum = fmaf(e, dvals[d], dnum);
        inum = fmaf(e, (float)d, inum);
    }
    float invs = 1.f / s;
    float depth = dnum * invs;
    float didx = inum * invs;
    int id = (int)didx;
    id = min(max(id, 0), D_ - 1);
    float conf = 0.f;
    for (int k = id - 1; k <= id + 2; ++k)
        if (k >= 0 && k < D_) conf += __expf(cost[k * HW_ + pix] - mx);
    conf *= invs;
    out[pix] = depth;
    out[HW_ + pix] = conf;
}

// ---------------------------------------------------------------------------
extern "C" void kernel_launch(void* const* d_in, const int* in_sizes, int n_in,
                              void* d_out, int out_size, void* d_ws, size_t ws_size,
                              hipStream_t stream) {
    const float* ref_feats = (const float*)d_in[0];   // (4,1,32,128,160)
    const float* src_feats = (const float*)d_in[1];   // (4,1,32,128,160)
    const float* proj      = (const float*)d_in[2];   // (1,5,2,4,4)
    const float* dvals     = (const float*)d_in[3];   // (1,48)
    const float* wreg      = (const float*)d_in[5];   // (1,32,3,3,3)
    float* out = (float*)d_out;                       // depth(20480) ++ conf(20480)

    char* ws = (char*)d_ws;
    float* rt   = (float*)ws;                          // 48 floats (pad to 1KB)
    float* srcT = (float*)(ws + 1024);                 // 10.5 MB
    float* refT = srcT + (size_t)4 * HW_ * C_;         // 10.5 MB
    float* Gx   = refT + (size_t)4 * HW_ * C_;         // 9*DHW*4 = 35.4 MB
    float* cost = Gx + (size_t)9 * DHW_;               // 3.9 MB

    proj_kernel<<<1, 64, 0, stream>>>(proj, rt);
    transpose_kernel<<<(4 * HW_) / 256, 256, 0, stream>>>(src_feats, srcT);
    transpose_kernel<<<(4 * HW_) / 256, 256, 0, stream>>>(ref_feats, refT);
    warp_fold_x_kernel<<<D_ * H_, 256, 0, stream>>>(srcT, refT, rt, dvals, wreg, Gx);
    gather9_kernel<<<(DHW_ / 4) / 256, 256, 0, stream>>>(Gx, cost);
    softmax_kernel<<<HW_ / 256, 256, 0, stream>>>(cost, dvals, out);
}

// Round 6
// 212.365 us; speedup vs baseline: 2.0671x; 1.0228x over previous
//
#include <hip/hip_runtime.h>
#include <math.h>

#define H_ 128
#define W_ 160
#define D_ 48
#define C_ 32
#define K27 27
#define HW_ (H_ * W_)
#define DHW_ (D_ * HW_)
#define CHW_ (C_ * HW_)

typedef float f4 __attribute__((ext_vector_type(4)));

// ---------------------------------------------------------------------------
// Kernel 1: projection setup. For each src view v=1..4 store 12 floats:
// rot(9) + trans(3) of  src_proj_new @ inv(ref_proj_new).
// ---------------------------------------------------------------------------
__device__ __forceinline__ void build_proj(const float* __restrict__ P, int v,
                                           double M[4][4]) {
    const float* E = P + (v * 2 + 0) * 16;
    const float* K = P + (v * 2 + 1) * 16;
    for (int i = 0; i < 3; i++)
        for (int j = 0; j < 4; j++) {
            double s = 0.0;
            for (int k = 0; k < 3; k++) s += (double)K[i * 4 + k] * (double)E[k * 4 + j];
            M[i][j] = s;
        }
    for (int j = 0; j < 4; j++) M[3][j] = (double)E[12 + j];
}

__global__ void proj_kernel(const float* __restrict__ P, float* __restrict__ rt) {
    if (threadIdx.x != 0) return;
    double M0[4][4];
    build_proj(P, 0, M0);
    double a[4][8];
    for (int i = 0; i < 4; i++)
        for (int j = 0; j < 4; j++) {
            a[i][j] = M0[i][j];
            a[i][4 + j] = (i == j) ? 1.0 : 0.0;
        }
    for (int col = 0; col < 4; ++col) {
        int piv = col;
        double best = fabs(a[col][col]);
        for (int r = col + 1; r < 4; r++) {
            double vv = fabs(a[r][col]);
            if (vv > best) { best = vv; piv = r; }
        }
        if (piv != col)
            for (int j = 0; j < 8; j++) {
                double t = a[col][j]; a[col][j] = a[piv][j]; a[piv][j] = t;
            }
        double inv = 1.0 / a[col][col];
        for (int j = 0; j < 8; j++) a[col][j] *= inv;
        for (int r = 0; r < 4; r++)
            if (r != col) {
                double f = a[r][col];
                for (int j = 0; j < 8; j++) a[r][j] -= f * a[col][j];
            }
    }
    double Minv[4][4];
    for (int i = 0; i < 4; i++)
        for (int j = 0; j < 4; j++) Minv[i][j] = a[i][4 + j];

    for (int v = 1; v < 5; ++v) {
        double Mv[4][4];
        build_proj(P, v, Mv);
        double Pm[4][4];
        for (int i = 0; i < 4; i++)
            for (int j = 0; j < 4; j++) {
                double s = 0.0;
                for (int k = 0; k < 4; k++) s += Mv[i][k] * Minv[k][j];
                Pm[i][j] = s;
            }
        float* o = rt + (v - 1) * 12;
        o[0] = (float)Pm[0][0]; o[1] = (float)Pm[0][1]; o[2] = (float)Pm[0][2];
        o[3] = (float)Pm[1][0]; o[4] = (float)Pm[1][1]; o[5] = (float)Pm[1][2];
        o[6] = (float)Pm[2][0]; o[7] = (float)Pm[2][1]; o[8] = (float)Pm[2][2];
        o[9] = (float)Pm[0][3]; o[10] = (float)Pm[1][3]; o[11] = (float)Pm[2][3];
    }
}

// ---------------------------------------------------------------------------
// Kernel 1b: transpose both tensors [4][C][HW] -> [4][HW][C] in one launch.
// ---------------------------------------------------------------------------
__global__ void transpose2_kernel(const float* __restrict__ sf,
                                  const float* __restrict__ rf,
                                  float* __restrict__ so,
                                  float* __restrict__ ro) {
    int t = blockIdx.x * blockDim.x + threadIdx.x;
    const float* in = sf;
    float* out = so;
    if (t >= 4 * HW_) {
        t -= 4 * HW_;
        in = rf;
        out = ro;
    }
    int pix = t % HW_;
    int v = t / HW_;
    float vals[C_];
#pragma unroll
    for (int c = 0; c < C_; c++) vals[c] = in[(size_t)v * CHW_ + c * HW_ + pix];
    f4* o = (f4*)(out + ((size_t)v * HW_ + pix) * C_);
#pragma unroll
    for (int q = 0; q < 8; q++) {
        f4 w = {vals[4 * q], vals[4 * q + 1], vals[4 * q + 2], vals[4 * q + 3]};
        o[q] = w;
    }
}

// ---------------------------------------------------------------------------
// Kernel 2: one image row (d,y) per block; 3 batches of 64 voxels x 4 lanes.
// Per quad (voxel), lane cgrp computes proj/weights/offsets for VIEW cgrp
// only; the quad exchanges them via __shfl (32 bpermutes) -- removes the 4x
// replication of proj math. Then each lane blends its 8 channels for all 4
// views, writes accT, and phase 2/3 fold channels + x-axis into 9 planes.
// ---------------------------------------------------------------------------
__global__ void __launch_bounds__(256)
warp_fold_x_kernel(const float* __restrict__ srcT,
                   const float* __restrict__ refT,
                   const float* __restrict__ rt,
                   const float* __restrict__ dvals,
                   const float* __restrict__ wreg,
                   float* __restrict__ Gx) {
    __shared__ float accT[8][64][4];   // 8 KB
    __shared__ float gLDS[K27][164];   // 17.7 KB

    int t = threadIdx.x;
    int lane = t & 63;
    int qb = lane & 60;        // quad base lane (within wave)
    int vox = t >> 2;          // 0..63
    int cgrp = t & 3;          // channel group AND "my view" for param calc
    int blk = blockIdx.x;      // 0..6143
    int d = blk >> 7;
    int y = blk & 127;
    float depth = dvals[d];
    float yf = (float)y;
    int rowbase = d * HW_ + y * W_;

    // per-thread (view = cgrp) linear-in-x projection coefficients
    const float* m = rt + cgrp * 12;
    float Ax = fmaf(fmaf(m[1], yf, m[2]), depth, m[9]);
    float Bx = m[0] * depth;
    float Ay = fmaf(fmaf(m[4], yf, m[5]), depth, m[10]);
    float By = m[3] * depth;
    float Az = fmaf(fmaf(m[7], yf, m[8]), depth, m[11]);
    float Bz = m[6] * depth;

#pragma unroll 1
    for (int b = 0; b < 3; b++) {
        int vg = b * 64 + vox;            // 0..191
        int x = vg - 1;                   // -1..190 (valid: 0..159)
        bool xvalid = (x >= 0) && (x < W_);

        // ---- params for (my voxel, my view) ----
        float W00, W10, W01, W11;
        int O00, O10, O01, O11;
        {
            float xf = (float)x;
            float pz = fmaf(Bz, xf, Az);
            float iz = 1.f / pz;
            float px = fmaf(Bx, xf, Ax) * iz;
            float py = fmaf(By, xf, Ay) * iz;
            float x0f = floorf(px), y0f = floorf(py);
            float wx = px - x0f, wy = py - y0f;
            int x0 = (int)x0f, y0 = (int)y0f;
            int x1 = x0 + 1, y1 = y0 + 1;
            W00 = (1.f - wx) * (1.f - wy);
            W10 = wx * (1.f - wy);
            W01 = (1.f - wx) * wy;
            W11 = wx * wy;
            bool vx0 = (x0 >= 0) && (x0 < W_);
            bool vx1 = (x1 >= 0) && (x1 < W_);
            bool vy0 = (y0 >= 0) && (y0 < H_);
            bool vy1 = (y1 >= 0) && (y1 < H_);
            if (!(vx0 && vy0)) W00 = 0.f;
            if (!(vx1 && vy0)) W10 = 0.f;
            if (!(vx0 && vy1)) W01 = 0.f;
            if (!(vx1 && vy1)) W11 = 0.f;
            int cx0 = min(max(x0, 0), W_ - 1);
            int cx1 = min(max(x1, 0), W_ - 1);
            int cy0 = min(max(y0, 0), H_ - 1);
            int cy1 = min(max(y1, 0), H_ - 1);
            O00 = (cy0 * W_ + cx0) * C_;
            O10 = (cy0 * W_ + cx1) * C_;
            O01 = (cy1 * W_ + cx0) * C_;
            O11 = (cy1 * W_ + cx1) * C_;
        }

        f4 acc0 = (f4){0.f, 0.f, 0.f, 0.f};
        f4 acc1 = (f4){0.f, 0.f, 0.f, 0.f};

        if (xvalid) {
            int pix = y * W_ + x;
            const float* rbase = refT + (size_t)pix * C_ + cgrp * 8;
#pragma unroll 2
            for (int v = 0; v < 4; v++) {
                float w00 = __shfl(W00, qb + v);
                float w10 = __shfl(W10, qb + v);
                float w01 = __shfl(W01, qb + v);
                float w11 = __shfl(W11, qb + v);
                int o00 = __shfl(O00, qb + v);
                int o10 = __shfl(O10, qb + v);
                int o01 = __shfl(O01, qb + v);
                int o11 = __shfl(O11, qb + v);

                const float* sv = srcT + (size_t)v * HW_ * C_ + cgrp * 8;
                const f4* p00 = (const f4*)(sv + o00);
                const f4* p10 = (const f4*)(sv + o10);
                const f4* p01 = (const f4*)(sv + o01);
                const f4* p11 = (const f4*)(sv + o11);
                const f4* pr  = (const f4*)(rbase + (size_t)v * HW_ * C_);

                f4 a00 = p00[0], b00 = p00[1];
                f4 a10 = p10[0], b10 = p10[1];
                f4 a01 = p01[0], b01 = p01[1];
                f4 a11 = p11[0], b11 = p11[1];
                f4 r0 = pr[0],  r1 = pr[1];

                f4 sv0 = a00 * w00 + a10 * w10 + a01 * w01 + a11 * w11;
                f4 sv1 = b00 * w00 + b10 * w10 + b01 * w01 + b11 * w11;
                acc0 += r0 * sv0;
                acc1 += r1 * sv1;
            }
            acc0 *= 0.25f;
            acc1 *= 0.25f;
        }

        int cq0 = cgrp * 2;
        *(f4*)&accT[cq0][vox][0] = acc0;
        *(f4*)&accT[cq0 + 1][vox][0] = acc1;
        __syncthreads();

        // ---- phase 2: fold channels, wave-uniform tap ranges ----
        int fvox = t & 63;
        int kg = t >> 6;                   // 0..3
        int fvg = b * 64 + fvox;
        float av[C_];
#pragma unroll
        for (int cq = 0; cq < 8; cq++)
            *(f4*)&av[cq * 4] = *(const f4*)&accT[cq][fvox][0];

        if (fvg < 162) {
            int kstart = kg * 7;
            int kend = min(kstart + 7, K27);
#pragma unroll 1
            for (int k = kstart; k < kend; k++) {
                int ku = __builtin_amdgcn_readfirstlane(k);
                float g = 0.f;
#pragma unroll
                for (int c = 0; c < C_; c++) g = fmaf(wreg[c * K27 + ku], av[c], g);
                gLDS[ku][fvg] = g;
            }
        }
        __syncthreads();   // protects accT before next batch overwrites
    }

    // ---- phase 3: x-shift-add -> 9 planes ----
    if (t < W_) {
        int x = t;
#pragma unroll
        for (int j = 0; j < 9; j++) {
            float s = gLDS[j * 3 + 0][x] + gLDS[j * 3 + 1][x + 1] +
                      gLDS[j * 3 + 2][x + 2];
            Gx[(size_t)j * DHW_ + rowbase + x] = s;
        }
    }
}

// ---------------------------------------------------------------------------
// Kernel 3: gather over 9 planes with (d,y)-shifts only; x stays aligned.
// ---------------------------------------------------------------------------
__global__ void gather9_kernel(const float* __restrict__ Gx,
                               float* __restrict__ cost) {
    int t = blockIdx.x * blockDim.x + threadIdx.x;
    if (t >= DHW_ / 4) return;
    int idx = t * 4;
    int x = idx % W_;            // multiple of 4
    int y = (idx / W_) % H_;
    int d = idx / HW_;
    f4 acc = (f4){0.f, 0.f, 0.f, 0.f};
#pragma unroll
    for (int kd = 0; kd < 3; kd++) {
        int dd = d + kd - 1;
        if ((unsigned)dd >= (unsigned)D_) continue;
#pragma unroll
        for (int kh = 0; kh < 3; kh++) {
            int yy = y + kh - 1;
            if ((unsigned)yy >= (unsigned)H_) continue;
            int j = kd * 3 + kh;
            acc += *(const f4*)(Gx + (size_t)j * DHW_ + dd * HW_ + yy * W_ + x);
        }
    }
    *(f4*)(cost + idx) = acc;
}

// ---------------------------------------------------------------------------
// Kernel 4: softmax over D per pixel-quad (f4), unrolled for load overlap.
// ---------------------------------------------------------------------------
__global__ void softmax_kernel(const float* __restrict__ cost,
                               const float* __restrict__ dvals,
                               float* __restrict__ out) {
    int q = blockIdx.x * blockDim.x + threadIdx.x;
    if (q >= HW_ / 4) return;
    int base = q * 4;

    f4 mx = (f4){-1e30f, -1e30f, -1e30f, -1e30f};
#pragma unroll 8
    for (int d = 0; d < D_; d++) {
        f4 c = *(const f4*)(cost + (size_t)d * HW_ + base);
#pragma unroll
        for (int j = 0; j < 4; j++) mx[j] = fmaxf(mx[j], c[j]);
    }
    f4 s = (f4){0.f, 0.f, 0.f, 0.f};
    f4 dn = (f4){0.f, 0.f, 0.f, 0.f};
    f4 in = (f4){0.f, 0.f, 0.f, 0.f};
#pragma unroll 8
    for (int d = 0; d < D_; d++) {
        f4 c = *(const f4*)(cost + (size_t)d * HW_ + base);
        float dv = dvals[d];
#pragma unroll
        for (int j = 0; j < 4; j++) {
            float e = __expf(c[j] - mx[j]);
            s[j] += e;
            dn[j] = fmaf(e, dv, dn[j]);
            in[j] = fmaf(e, (float)d, in[j]);
        }
    }
#pragma unroll
    for (int j = 0; j < 4; j++) {
        float invs = 1.f / s[j];
        float depth = dn[j] * invs;
        int id = (int)(in[j] * invs);
        id = min(max(id, 0), D_ - 1);
        float conf = 0.f;
#pragma unroll 1
        for (int k = id - 1; k <= id + 2; ++k)
            if (k >= 0 && k < D_) conf += __expf(cost[(size_t)k * HW_ + base + j] - mx[j]);
        out[base + j] = depth;
        out[HW_ + base + j] = conf * invs;
    }
}

// ---------------------------------------------------------------------------
extern "C" void kernel_launch(void* const* d_in, const int* in_sizes, int n_in,
                              void* d_out, int out_size, void* d_ws, size_t ws_size,
                              hipStream_t stream) {
    const float* ref_feats = (const float*)d_in[0];   // (4,1,32,128,160)
    const float* src_feats = (const float*)d_in[1];   // (4,1,32,128,160)
    const float* proj      = (const float*)d_in[2];   // (1,5,2,4,4)
    const float* dvals     = (const float*)d_in[3];   // (1,48)
    const float* wreg      = (const float*)d_in[5];   // (1,32,3,3,3)
    float* out = (float*)d_out;                       // depth(20480) ++ conf(20480)

    char* ws = (char*)d_ws;
    float* rt   = (float*)ws;                          // 48 floats (pad to 1KB)
    float* srcT = (float*)(ws + 1024);                 // 10.5 MB
    float* refT = srcT + (size_t)4 * HW_ * C_;         // 10.5 MB
    float* Gx   = refT + (size_t)4 * HW_ * C_;         // 9*DHW*4 = 35.4 MB
    float* cost = Gx + (size_t)9 * DHW_;               // 3.9 MB

    proj_kernel<<<1, 64, 0, stream>>>(proj, rt);
    transpose2_kernel<<<(8 * HW_) / 256, 256, 0, stream>>>(src_feats, ref_feats,
                                                           srcT, refT);
    warp_fold_x_kernel<<<D_ * H_, 256, 0, stream>>>(srcT, refT, rt, dvals, wreg, Gx);
    gather9_kernel<<<(DHW_ / 4) / 256, 256, 0, stream>>>(Gx, cost);
    softmax_kernel<<<(HW_ / 4) / 256, 256, 0, stream>>>(cost, dvals, out);
}